// Round 1
// baseline (23020.053 us; speedup 1.0000x reference)
//
#include <hip/hip_runtime.h>
#include <hip/hip_cooperative_groups.h>
#include <cmath>

namespace cg = cooperative_groups;

// Problem constants
#define B_ 64
#define T_ 512
#define I_ 1024
#define H_ 1024

// ---------------------------------------------------------------------------
// Kernel 1: xw[m, n] = sum_k x[m,k] * W[n,k] + bW[n]   (M=32768, N=1024, K=1024)
// Written into the out1 region of d_out (row = b*T + t, col = h).
// Classic fp32 tiled SGEMM: 128x128 tile, BK=8, 256 threads, 8x8 per thread.
// ---------------------------------------------------------------------------
#define TS 128
#define KS 8

__global__ __launch_bounds__(256) void gemm_xw(const float* __restrict__ x,
                                               const float* __restrict__ W,
                                               const float* __restrict__ bW,
                                               float* __restrict__ out) {
    __shared__ float As[KS][TS];  // [kk][m]
    __shared__ float Bs[KS][TS];  // [kk][n]

    const int tid = threadIdx.x;
    const int tx = tid & 15;   // 0..15  (n micro-tile)
    const int ty = tid >> 4;   // 0..15  (m micro-tile)
    const int m0 = blockIdx.y * TS;
    const int n0 = blockIdx.x * TS;

    // staging assignment: thread loads one float4 of A and one of B per K-chunk
    const int lr = tid >> 1;          // 0..127 : row within tile
    const int lk = (tid & 1) * 4;     // 0 or 4 : k offset within chunk

    const float* xa = x + (size_t)(m0 + lr) * I_ + lk;
    const float* wb = W + (size_t)(n0 + lr) * I_ + lk;

    float acc[8][8] = {};

    for (int k0 = 0; k0 < I_; k0 += KS) {
        float4 a = *(const float4*)(xa + k0);
        float4 bv = *(const float4*)(wb + k0);
        __syncthreads();  // protect LDS reads of previous iteration
        As[lk + 0][lr] = a.x;  As[lk + 1][lr] = a.y;
        As[lk + 2][lr] = a.z;  As[lk + 3][lr] = a.w;
        Bs[lk + 0][lr] = bv.x; Bs[lk + 1][lr] = bv.y;
        Bs[lk + 2][lr] = bv.z; Bs[lk + 3][lr] = bv.w;
        __syncthreads();
#pragma unroll
        for (int kk = 0; kk < KS; ++kk) {
            float av[8], bw8[8];
            *(float4*)&av[0]  = *(const float4*)&As[kk][ty * 8];
            *(float4*)&av[4]  = *(const float4*)&As[kk][ty * 8 + 4];
            *(float4*)&bw8[0] = *(const float4*)&Bs[kk][tx * 8];
            *(float4*)&bw8[4] = *(const float4*)&Bs[kk][tx * 8 + 4];
#pragma unroll
            for (int i = 0; i < 8; ++i)
#pragma unroll
                for (int j = 0; j < 8; ++j)
                    acc[i][j] += av[i] * bw8[j];
        }
    }

    // epilogue: add bias, store
    float bias[8];
    *(float4*)&bias[0] = *(const float4*)&bW[n0 + tx * 8];
    *(float4*)&bias[4] = *(const float4*)&bW[n0 + tx * 8 + 4];
#pragma unroll
    for (int i = 0; i < 8; ++i) {
        float* o = out + (size_t)(m0 + ty * 8 + i) * H_ + n0 + tx * 8;
        float4 v0, v1;
        v0.x = acc[i][0] + bias[0]; v0.y = acc[i][1] + bias[1];
        v0.z = acc[i][2] + bias[2]; v0.w = acc[i][3] + bias[3];
        v1.x = acc[i][4] + bias[4]; v1.y = acc[i][5] + bias[5];
        v1.z = acc[i][6] + bias[6]; v1.w = acc[i][7] + bias[7];
        *(float4*)(o)     = v0;
        *(float4*)(o + 4) = v1;
    }
}

// ---------------------------------------------------------------------------
// Kernel 2: persistent cooperative recurrence.
// 256 WGs x 256 threads. WG g owns output/state columns h in [4g, 4g+4).
// U rows for those columns live in LDS permanently (padded per k-quarter so
// the 4 hl-lanes hit distinct banks). State s[b][h] lives in a register of
// thread (b, hl). Per step:
//   (a) h3 = tanh(xw + s) for own (b,h); write to out1[b,t,h] (in place).
//   (b) grid.sync()  -- makes all h3 of step t visible device-wide.
//   (c) s = bU[h] + dot(h3[b, :], U[h, :]) : 4-lane group (same b) splits the
//       k-range into quarters, partials combined via 2 shfl_xor butterflies.
// ---------------------------------------------------------------------------
#define QPAD 264   // 256 data + 8 pad floats per k-quarter
#define ROWL (4 * QPAD)  // 1056 floats per U row in LDS

__global__ __launch_bounds__(256) void rnn_scan(const float* __restrict__ U,
                                                const float* __restrict__ bU,
                                                float* __restrict__ out) {
    __shared__ float Ul[4][ROWL];

    cg::grid_group grid = cg::this_grid();

    const int g = blockIdx.x;      // 0..255
    const int tid = threadIdx.x;
    const int b = tid >> 2;        // 0..63
    const int hl = tid & 3;        // 0..3
    const int h = g * 4 + hl;

    // --- load the 4 U rows into LDS (quarter-padded layout) ---
    {
        const int r = tid >> 6;             // 0..3 : which row
        const int kb = (tid & 63) * 16;     // 0..1008 : k base, 16 floats each
        const float* src = U + (size_t)(g * 4 + r) * H_ + kb;
        const int q = kb >> 8;
        const int off = kb & 255;
        float* dst = &Ul[r][q * QPAD + off];
#pragma unroll
        for (int j = 0; j < 16; j += 4)
            *(float4*)(dst + j) = *(const float4*)(src + j);
    }
    __syncthreads();

    const float bUh = bU[h];
    float s = 0.0f;

    float* out2 = out + (size_t)B_ * T_ * H_;
    const float* u0 = &Ul[0][hl * QPAD];
    const float* u1 = &Ul[1][hl * QPAD];
    const float* u2 = &Ul[2][hl * QPAD];
    const float* u3 = &Ul[3][hl * QPAD];

    for (int t = 0; t < T_; ++t) {
        const size_t rowoff = ((size_t)b * T_ + t) * H_;

        // (a) elementwise: xw (in out1) -> h3 (in place)
        float h3 = tanhf(out[rowoff + h] + s);
        out[rowoff + h] = h3;
        if (t == T_ - 1) out2[(size_t)b * H_ + h] = h3;

        // (b) device-wide barrier + fences
        grid.sync();

        // (c) next state: s = bU[h] + h3[b,:] . U[h,:]
        if (t < T_ - 1) {
            const float4* rp = (const float4*)(out + rowoff + hl * 256);
            float p0 = 0.f, p1 = 0.f, p2 = 0.f, p3 = 0.f;
#pragma unroll 8
            for (int kk = 0; kk < 64; ++kk) {
                float4 v = rp[kk];
                const int o = kk * 4;
                p0 += v.x * u0[o] + v.y * u0[o + 1] + v.z * u0[o + 2] + v.w * u0[o + 3];
                p1 += v.x * u1[o] + v.y * u1[o + 1] + v.z * u1[o + 2] + v.w * u1[o + 3];
                p2 += v.x * u2[o] + v.y * u2[o + 1] + v.z * u2[o + 2] + v.w * u2[o + 3];
                p3 += v.x * u3[o] + v.y * u3[o + 1] + v.z * u3[o + 2] + v.w * u3[o + 3];
            }
            // combine k-quarter partials across the 4-lane group (same b)
            p0 += __shfl_xor(p0, 1); p1 += __shfl_xor(p1, 1);
            p2 += __shfl_xor(p2, 1); p3 += __shfl_xor(p3, 1);
            p0 += __shfl_xor(p0, 2); p1 += __shfl_xor(p1, 2);
            p2 += __shfl_xor(p2, 2); p3 += __shfl_xor(p3, 2);
            const float r = (hl == 0) ? p0 : (hl == 1) ? p1 : (hl == 2) ? p2 : p3;
            s = bUh + r;
        }
    }
}

// ---------------------------------------------------------------------------
extern "C" void kernel_launch(void* const* d_in, const int* in_sizes, int n_in,
                              void* d_out, int out_size, void* d_ws, size_t ws_size,
                              hipStream_t stream) {
    const float* x  = (const float*)d_in[0];
    const float* W  = (const float*)d_in[1];
    const float* bW = (const float*)d_in[2];
    const float* U  = (const float*)d_in[3];
    const float* bU = (const float*)d_in[4];
    float* out = (float*)d_out;

    // Phase 1: xw -> out1 region of d_out
    dim3 g1(H_ / TS, (B_ * T_) / TS);  // (8, 256)
    gemm_xw<<<g1, dim3(256), 0, stream>>>(x, W, bW, out);

    // Phase 2: persistent cooperative scan
    void* args[] = {(void*)&U, (void*)&bU, (void*)&out};
    hipLaunchCooperativeKernel((void*)rnn_scan, dim3(256), dim3(256), args, 0,
                               stream);
}

// Round 2
// 8993.815 us; speedup vs baseline: 2.5595x; 2.5595x over previous
//
#include <hip/hip_runtime.h>
#include <cmath>

#define B_ 64
#define T_ 512
#define I_ 1024
#define H_ 1024

// ---------------------------------------------------------------------------
// Kernel 1: xw[m, n] = sum_k x[m,k] * W[n,k] + bW[n]   (M=32768, N=1024, K=1024)
// Written into the out1 region of d_out. 128x128 tile, BK=8, 8x8 per thread.
// ---------------------------------------------------------------------------
#define TS 128
#define KS 8

__global__ __launch_bounds__(256) void gemm_xw(const float* __restrict__ x,
                                               const float* __restrict__ W,
                                               const float* __restrict__ bW,
                                               float* __restrict__ out) {
    __shared__ float As[KS][TS];
    __shared__ float Bs[KS][TS];

    const int tid = threadIdx.x;
    const int tx = tid & 15;
    const int ty = tid >> 4;
    const int m0 = blockIdx.y * TS;
    const int n0 = blockIdx.x * TS;

    const int lr = tid >> 1;
    const int lk = (tid & 1) * 4;

    const float* xa = x + (size_t)(m0 + lr) * I_ + lk;
    const float* wb = W + (size_t)(n0 + lr) * I_ + lk;

    float acc[8][8] = {};

    for (int k0 = 0; k0 < I_; k0 += KS) {
        float4 a = *(const float4*)(xa + k0);
        float4 bv = *(const float4*)(wb + k0);
        __syncthreads();
        As[lk + 0][lr] = a.x;  As[lk + 1][lr] = a.y;
        As[lk + 2][lr] = a.z;  As[lk + 3][lr] = a.w;
        Bs[lk + 0][lr] = bv.x; Bs[lk + 1][lr] = bv.y;
        Bs[lk + 2][lr] = bv.z; Bs[lk + 3][lr] = bv.w;
        __syncthreads();
#pragma unroll
        for (int kk = 0; kk < KS; ++kk) {
            float av[8], bw8[8];
            *(float4*)&av[0]  = *(const float4*)&As[kk][ty * 8];
            *(float4*)&av[4]  = *(const float4*)&As[kk][ty * 8 + 4];
            *(float4*)&bw8[0] = *(const float4*)&Bs[kk][tx * 8];
            *(float4*)&bw8[4] = *(const float4*)&Bs[kk][tx * 8 + 4];
#pragma unroll
            for (int i = 0; i < 8; ++i)
#pragma unroll
                for (int j = 0; j < 8; ++j)
                    acc[i][j] += av[i] * bw8[j];
        }
    }

    float bias[8];
    *(float4*)&bias[0] = *(const float4*)&bW[n0 + tx * 8];
    *(float4*)&bias[4] = *(const float4*)&bW[n0 + tx * 8 + 4];
#pragma unroll
    for (int i = 0; i < 8; ++i) {
        float* o = out + (size_t)(m0 + ty * 8 + i) * H_ + n0 + tx * 8;
        float4 v0, v1;
        v0.x = acc[i][0] + bias[0]; v0.y = acc[i][1] + bias[1];
        v0.z = acc[i][2] + bias[2]; v0.w = acc[i][3] + bias[3];
        v1.x = acc[i][4] + bias[4]; v1.y = acc[i][5] + bias[5];
        v1.z = acc[i][6] + bias[6]; v1.w = acc[i][7] + bias[7];
        *(float4*)(o)     = v0;
        *(float4*)(o + 4) = v1;
    }
}

// ---------------------------------------------------------------------------
// Kernel 2: persistent recurrence, custom flag barrier + LDS-staged h3.
//
// 256 WGs x 256 threads; WG g owns h columns [4g, 4g+4). Thread = (b, hl).
// U rows live in LDS forever. h3 exchanged via double-buffered hx in d_ws,
// written/read with agent-scope relaxed atomics (sc1 path -> L3, no L2
// writeback fences). Barrier: per-block flag store (gen = t+1), block 0
// gathers 256 flags (one per thread) and releases a single `go` word.
// Phase (c): h3 staged through LDS in four 64KB k-chunks (double-buffered,
// register-prefetched), coalesced 8B/lane global loads.
//
// LDS layout for staged h3: row stride 272 floats, quarter stride 68
//   -> lane-consecutive b128 reads tile all 32 banks (2-way max).
// ---------------------------------------------------------------------------
#define QPAD 264          // U row: 4 quarters * 264 floats
#define ROWL (4 * QPAD)
#define QSTR 68           // staged h3 quarter stride (floats)
#define H3STRIDE 272      // staged h3 row stride = 4*68 (floats)

__global__ __launch_bounds__(256) void rnn_scan(const float* __restrict__ U,
                                                const float* __restrict__ bU,
                                                float* __restrict__ out,
                                                float* __restrict__ hx0,
                                                float* __restrict__ hx1,
                                                unsigned* __restrict__ flags,
                                                unsigned* __restrict__ go) {
    __shared__ float Ul[4][ROWL];                 // 16.9 KB
    __shared__ float h3l[2][64 * H3STRIDE];       // 139.3 KB

    const int g = blockIdx.x;
    const int tid = threadIdx.x;
    const int b = tid >> 2;        // 0..63
    const int hl = tid & 3;        // 0..3
    const int h = g * 4 + hl;

    // --- load the 4 U rows into LDS (quarter-padded layout) ---
    {
        const int r = tid >> 6;
        const int kb = (tid & 63) * 16;
        const float* src = U + (size_t)(g * 4 + r) * H_ + kb;
        const int q = kb >> 8;
        const int off = kb & 255;
        float* dst = &Ul[r][q * QPAD + off];
#pragma unroll
        for (int j = 0; j < 16; j += 4)
            *(float4*)(dst + j) = *(const float4*)(src + j);
    }
    __syncthreads();

    const float bUh = bU[h];
    float s = 0.0f;
    float* out2 = out + (size_t)B_ * T_ * H_;

    // writer-side hx indexing: h3[b][k=h] at dword chunk*16384 + b*256 + (h&255)
    const int wchunk = h >> 8;
    const int wcol = h & 255;

    // staging-side per-thread constants (chunk-local dword e = j*512 + tid*2)
    const int koff = (tid * 2) & 255;
    const int stq = koff >> 6;
    const int stkk = koff & 63;
    const int stb = (tid * 2) >> 8;               // 0 or 1
    const int ldsoff0 = stq * QSTR + stkk;

    for (int t = 0; t < T_; ++t) {
        const size_t rowoff = ((size_t)b * T_ + t) * H_;

        // (a) elementwise: xw (in out1) -> h3 (in place)
        float h3 = tanhf(out[rowoff + h] + s);
        out[rowoff + h] = h3;
        if (t == T_ - 1) {
            out2[(size_t)b * H_ + h] = h3;
            break;                                 // uniform across all blocks
        }

        float* hx = (t & 1) ? hx1 : hx0;
        __hip_atomic_store((unsigned*)hx + wchunk * 16384 + b * 256 + wcol,
                           __float_as_uint(h3), __ATOMIC_RELAXED,
                           __HIP_MEMORY_SCOPE_AGENT);

        // (b) custom grid barrier. __syncthreads drains vmcnt for every wave,
        // so the sc1 write-through stores above have completed to L3 before
        // any flag is raised.
        __syncthreads();
        const unsigned gen = (unsigned)(t + 1);
        if (tid == 0)
            __hip_atomic_store(&flags[g], gen, __ATOMIC_RELAXED,
                               __HIP_MEMORY_SCOPE_AGENT);
        if (g == 0) {
            while (__hip_atomic_load(&flags[tid], __ATOMIC_RELAXED,
                                     __HIP_MEMORY_SCOPE_AGENT) != gen) {}
            __syncthreads();
            if (tid == 0)
                __hip_atomic_store(go, gen, __ATOMIC_RELAXED,
                                   __HIP_MEMORY_SCOPE_AGENT);
        } else {
            if (tid == 0)
                while (__hip_atomic_load(go, __ATOMIC_RELAXED,
                                         __HIP_MEMORY_SCOPE_AGENT) != gen) {}
            __syncthreads();
        }

        // (c) staged GEMV: s = bU[h] + h3[b,:] . U[h,:]
        unsigned long long* hx8 = (unsigned long long*)hx;
        unsigned long long pf[32];
#pragma unroll
        for (int j = 0; j < 32; ++j)
            pf[j] = __hip_atomic_load(&hx8[j * 256 + tid], __ATOMIC_RELAXED,
                                      __HIP_MEMORY_SCOPE_AGENT);

        float p0 = 0.f, p1 = 0.f, p2 = 0.f, p3 = 0.f;
        for (int c = 0; c < 4; ++c) {
            const int bufsel = c & 1;
            // commit prefetched chunk c to LDS
#pragma unroll
            for (int j = 0; j < 32; ++j) {
                float2 w;
                w.x = __uint_as_float((unsigned)(pf[j] & 0xffffffffu));
                w.y = __uint_as_float((unsigned)(pf[j] >> 32));
                *(float2*)&h3l[bufsel][(2 * j + stb) * H3STRIDE + ldsoff0] = w;
            }
            __syncthreads();
            // prefetch chunk c+1 while computing chunk c
            if (c < 3) {
#pragma unroll
                for (int j = 0; j < 32; ++j)
                    pf[j] = __hip_atomic_load(&hx8[(c + 1) * 8192 + j * 256 + tid],
                                              __ATOMIC_RELAXED,
                                              __HIP_MEMORY_SCOPE_AGENT);
            }
            const float* hp = &h3l[bufsel][b * H3STRIDE + hl * QSTR];
            const float* u0 = &Ul[0][c * QPAD + hl * 64];
            const float* u1 = &Ul[1][c * QPAD + hl * 64];
            const float* u2 = &Ul[2][c * QPAD + hl * 64];
            const float* u3 = &Ul[3][c * QPAD + hl * 64];
#pragma unroll
            for (int kk = 0; kk < 64; kk += 4) {
                float4 hv = *(const float4*)(hp + kk);
                float4 a0 = *(const float4*)(u0 + kk);
                float4 a1 = *(const float4*)(u1 + kk);
                float4 a2 = *(const float4*)(u2 + kk);
                float4 a3 = *(const float4*)(u3 + kk);
                p0 += hv.x * a0.x + hv.y * a0.y + hv.z * a0.z + hv.w * a0.w;
                p1 += hv.x * a1.x + hv.y * a1.y + hv.z * a1.z + hv.w * a1.w;
                p2 += hv.x * a2.x + hv.y * a2.y + hv.z * a2.z + hv.w * a2.w;
                p3 += hv.x * a3.x + hv.y * a3.y + hv.z * a3.z + hv.w * a3.w;
            }
        }

        // combine k-quarter partials across the 4-lane group (same b)
        p0 += __shfl_xor(p0, 1); p1 += __shfl_xor(p1, 1);
        p2 += __shfl_xor(p2, 1); p3 += __shfl_xor(p3, 1);
        p0 += __shfl_xor(p0, 2); p1 += __shfl_xor(p1, 2);
        p2 += __shfl_xor(p2, 2); p3 += __shfl_xor(p3, 2);
        const float r = (hl == 0) ? p0 : (hl == 1) ? p1 : (hl == 2) ? p2 : p3;
        s = bUh + r;
    }
}

// ---------------------------------------------------------------------------
extern "C" void kernel_launch(void* const* d_in, const int* in_sizes, int n_in,
                              void* d_out, int out_size, void* d_ws, size_t ws_size,
                              hipStream_t stream) {
    const float* x  = (const float*)d_in[0];
    const float* W  = (const float*)d_in[1];
    const float* bW = (const float*)d_in[2];
    const float* U  = (const float*)d_in[3];
    const float* bU = (const float*)d_in[4];
    float* out = (float*)d_out;

    // workspace carve-up: two 256KB hx buffers + flags + go (gens never
    // collide with the 0xAA poison, so no init required)
    float* hx0 = (float*)d_ws;
    float* hx1 = hx0 + (size_t)B_ * H_;
    unsigned* flags = (unsigned*)(hx1 + (size_t)B_ * H_);
    unsigned* go = flags + 256;

    dim3 g1(H_ / TS, (B_ * T_) / TS);
    gemm_xw<<<g1, dim3(256), 0, stream>>>(x, W, bW, out);

    void* args[] = {(void*)&U, (void*)&bU, (void*)&out,
                    (void*)&hx0, (void*)&hx1, (void*)&flags, (void*)&go};
    hipLaunchCooperativeKernel((void*)rnn_scan, dim3(256), dim3(256), args, 0,
                               stream);
}

// Round 3
// 5012.257 us; speedup vs baseline: 4.5928x; 1.7944x over previous
//
#include <hip/hip_runtime.h>
#include <cmath>

#define B_ 64
#define T_ 512
#define I_ 1024
#define H_ 1024

// ---------------------------------------------------------------------------
// Kernel 1: xw[m, n] = sum_k x[m,k] * W[n,k] + bW[n]   (M=32768, N=1024, K=1024)
// Written into the out1 region of d_out. 128x128 tile, BK=8, 8x8 per thread.
// ---------------------------------------------------------------------------
#define TS 128
#define KS 8

__global__ __launch_bounds__(256) void gemm_xw(const float* __restrict__ x,
                                               const float* __restrict__ W,
                                               const float* __restrict__ bW,
                                               float* __restrict__ out) {
    __shared__ float As[KS][TS];
    __shared__ float Bs[KS][TS];

    const int tid = threadIdx.x;
    const int tx = tid & 15;
    const int ty = tid >> 4;
    const int m0 = blockIdx.y * TS;
    const int n0 = blockIdx.x * TS;

    const int lr = tid >> 1;
    const int lk = (tid & 1) * 4;

    const float* xa = x + (size_t)(m0 + lr) * I_ + lk;
    const float* wb = W + (size_t)(n0 + lr) * I_ + lk;

    float acc[8][8] = {};

    for (int k0 = 0; k0 < I_; k0 += KS) {
        float4 a = *(const float4*)(xa + k0);
        float4 bv = *(const float4*)(wb + k0);
        __syncthreads();
        As[lk + 0][lr] = a.x;  As[lk + 1][lr] = a.y;
        As[lk + 2][lr] = a.z;  As[lk + 3][lr] = a.w;
        Bs[lk + 0][lr] = bv.x; Bs[lk + 1][lr] = bv.y;
        Bs[lk + 2][lr] = bv.z; Bs[lk + 3][lr] = bv.w;
        __syncthreads();
#pragma unroll
        for (int kk = 0; kk < KS; ++kk) {
            float av[8], bw8[8];
            *(float4*)&av[0]  = *(const float4*)&As[kk][ty * 8];
            *(float4*)&av[4]  = *(const float4*)&As[kk][ty * 8 + 4];
            *(float4*)&bw8[0] = *(const float4*)&Bs[kk][tx * 8];
            *(float4*)&bw8[4] = *(const float4*)&Bs[kk][tx * 8 + 4];
#pragma unroll
            for (int i = 0; i < 8; ++i)
#pragma unroll
                for (int j = 0; j < 8; ++j)
                    acc[i][j] += av[i] * bw8[j];
        }
    }

    float bias[8];
    *(float4*)&bias[0] = *(const float4*)&bW[n0 + tx * 8];
    *(float4*)&bias[4] = *(const float4*)&bW[n0 + tx * 8 + 4];
#pragma unroll
    for (int i = 0; i < 8; ++i) {
        float* o = out + (size_t)(m0 + ty * 8 + i) * H_ + n0 + tx * 8;
        float4 v0, v1;
        v0.x = acc[i][0] + bias[0]; v0.y = acc[i][1] + bias[1];
        v0.z = acc[i][2] + bias[2]; v0.w = acc[i][3] + bias[3];
        v1.x = acc[i][4] + bias[4]; v1.y = acc[i][5] + bias[5];
        v1.z = acc[i][6] + bias[6]; v1.w = acc[i][7] + bias[7];
        *(float4*)(o)     = v0;
        *(float4*)(o + 4) = v1;
    }
}

// ---------------------------------------------------------------------------
// Kernel 2: persistent recurrence. 256 WGs x 256 threads; WG g owns h cols
// [4g,4g+4). U (4 rows) resident in LDS, conflict-free interleaved layout.
// h3 exchanged via double-buffered hx (d_ws) with agent-scope relaxed
// atomics (L3-coherent). Custom flag barrier (block0 gathers, go word).
//
// GEMV: thread (bgrp=tid>>4, kq=tid&15) computes partials for rows
// b=4*bgrp..+4, all 4 cols, k in {m*32 + 2kq, m*32 + 2kq+1 : m=0..31}.
// h3 slices read straight from hx (coalesced 8B atomic loads, 4-deep
// prefetch); U from LDS (banks (2m+2kq) mod 32 -> conflict-free).
// 16-way k-reduction: 4 shfl_xor butterflies over the kq lane bits; the
// result for (b=tid>>2, hl=tid&3) lands on thread tid = the tanh owner.
// ---------------------------------------------------------------------------
#define UROW 1088   // 32 chunks * 34 floats (32 data + 2 pad)

typedef unsigned long long ull;

__device__ __forceinline__ ull aload(const ull* p) {
    return __hip_atomic_load(p, __ATOMIC_RELAXED, __HIP_MEMORY_SCOPE_AGENT);
}

__global__ __launch_bounds__(256) void rnn_scan(const float* __restrict__ U,
                                                const float* __restrict__ bU,
                                                float* __restrict__ out,
                                                float* __restrict__ hx0,
                                                float* __restrict__ hx1,
                                                unsigned* __restrict__ flags,
                                                unsigned* __restrict__ go) {
    __shared__ float Ul[4][UROW];

    const int g = blockIdx.x;
    const int tid = threadIdx.x;
    const int b = tid >> 2;        // tanh identity
    const int hl = tid & 3;
    const int h = g * 4 + hl;

    // --- stage U rows into LDS, chunk-interleaved layout ---
    {
        const int r = tid >> 6;             // 0..3
        const int kk = (tid & 63) * 16;     // 16 consecutive k
        const float* src = U + (size_t)(g * 4 + r) * H_ + kk;
        const int m = kk >> 5;              // chunk
        const int w = kk & 31;              // 0 or 16
        float* dst = &Ul[r][m * 34 + w];
#pragma unroll
        for (int j = 0; j < 16; j += 4)
            *(float4*)(dst + j) = *(const float4*)(src + j);
    }
    __syncthreads();

    const float bUh = bU[h];
    float s = 0.0f;
    float* out2 = out + (size_t)B_ * T_ * H_;

    const int bgrp = tid >> 4;     // 0..15
    const int kq = tid & 15;       // 0..15
    const int r0 = bgrp * 4;

    float xwv = out[(size_t)b * T_ * H_ + h];   // xw for t=0

    for (int t = 0; t < T_; ++t) {
        // (a) elementwise: h3 = tanh(xw + s); out1 in place
        const size_t rowoff = ((size_t)b * T_ + t) * H_;
        float h3 = tanhf(xwv + s);
        out[rowoff + h] = h3;
        if (t == T_ - 1) {
            out2[(size_t)b * H_ + h] = h3;
            break;
        }

        float* hx = (t & 1) ? hx1 : hx0;
        __hip_atomic_store((unsigned*)hx + b * H_ + h, __float_as_uint(h3),
                           __ATOMIC_RELAXED, __HIP_MEMORY_SCOPE_AGENT);

        // (b) grid barrier (syncthreads drains vmcnt before flag raise)
        __syncthreads();
        const unsigned gen = (unsigned)(t + 1);
        if (tid == 0)
            __hip_atomic_store(&flags[g], gen, __ATOMIC_RELAXED,
                               __HIP_MEMORY_SCOPE_AGENT);
        if (g == 0) {
            while (__hip_atomic_load(&flags[tid], __ATOMIC_RELAXED,
                                     __HIP_MEMORY_SCOPE_AGENT) != gen) {}
            __syncthreads();
            if (tid == 0)
                __hip_atomic_store(go, gen, __ATOMIC_RELAXED,
                                   __HIP_MEMORY_SCOPE_AGENT);
        } else {
            if (tid == 0)
                while (__hip_atomic_load(go, __ATOMIC_RELAXED,
                                         __HIP_MEMORY_SCOPE_AGENT) != gen) {}
            __syncthreads();
        }

        // prefetch next step's xw (plain load; row owned by this thread)
        xwv = out[rowoff + H_ + h];   // (b, t+1) row

        // (c) GEMV partials: rows r0..r0+3, cols 0..3, k = m*32 + 2kq + {0,1}
        const ull* hx8 = (const ull*)hx;
        ull pf[4][4];
#pragma unroll
        for (int d = 0; d < 4; ++d)
#pragma unroll
            for (int i = 0; i < 4; ++i)
                pf[d][i] = aload(hx8 + (size_t)(r0 + i) * 512 + d * 16 + kq);

        float acc[4][4] = {};
#pragma unroll
        for (int m = 0; m < 32; ++m) {
            const int slot = m & 3;
            float2 hh[4];
#pragma unroll
            for (int i = 0; i < 4; ++i) {
                ull v = pf[slot][i];
                hh[i].x = __uint_as_float((unsigned)(v & 0xffffffffu));
                hh[i].y = __uint_as_float((unsigned)(v >> 32));
            }
            if (m < 28) {
#pragma unroll
                for (int i = 0; i < 4; ++i)
                    pf[slot][i] =
                        aload(hx8 + (size_t)(r0 + i) * 512 + (m + 4) * 16 + kq);
            }
#pragma unroll
            for (int c = 0; c < 4; ++c) {
                float2 uu = *(const float2*)&Ul[c][m * 34 + kq * 2];
#pragma unroll
                for (int i = 0; i < 4; ++i)
                    acc[i][c] += hh[i].x * uu.x + hh[i].y * uu.y;
            }
        }

        // 16-way k-reduction over the kq lane bits
#pragma unroll
        for (int i = 0; i < 4; ++i)
#pragma unroll
            for (int c = 0; c < 4; ++c) {
                float v = acc[i][c];
                v += __shfl_xor(v, 1);
                v += __shfl_xor(v, 2);
                v += __shfl_xor(v, 4);
                v += __shfl_xor(v, 8);
                acc[i][c] = v;
            }

        // select this thread's (b,hl) = (r0 + (kq>>2), kq&3)
        float r = acc[0][0];
#pragma unroll
        for (int i = 0; i < 4; ++i)
#pragma unroll
            for (int c = 0; c < 4; ++c)
                if (((kq >> 2) == i) && ((kq & 3) == c)) r = acc[i][c];

        s = bUh + r;
    }
}

// ---------------------------------------------------------------------------
extern "C" void kernel_launch(void* const* d_in, const int* in_sizes, int n_in,
                              void* d_out, int out_size, void* d_ws, size_t ws_size,
                              hipStream_t stream) {
    const float* x  = (const float*)d_in[0];
    const float* W  = (const float*)d_in[1];
    const float* bW = (const float*)d_in[2];
    const float* U  = (const float*)d_in[3];
    const float* bU = (const float*)d_in[4];
    float* out = (float*)d_out;

    float* hx0 = (float*)d_ws;
    float* hx1 = hx0 + (size_t)B_ * H_;
    unsigned* flags = (unsigned*)(hx1 + (size_t)B_ * H_);
    unsigned* go = flags + 256;

    dim3 g1(H_ / TS, (B_ * T_) / TS);
    gemm_xw<<<g1, dim3(256), 0, stream>>>(x, W, bW, out);

    void* args[] = {(void*)&U, (void*)&bU, (void*)&out,
                    (void*)&hx0, (void*)&hx1, (void*)&flags, (void*)&go};
    hipLaunchCooperativeKernel((void*)rnn_scan, dim3(256), dim3(256), args, 0,
                               stream);
}